// Round 7
// baseline (84.149 us; speedup 1.0000x reference)
//
#include <hip/hip_runtime.h>

#define NQ 10

typedef float f32x2 __attribute__((ext_vector_type(2)));
struct cplx2 { f32x2 x, y; };  // .x/.y = real/imag; each f32x2 = (sample0, sample1)

// ===== permlane swap (VALU pipe, replaces ds_bpermute for masks 16/32) =====
// {A,B} = permlaneN_swap(v,v):
//   A[l] = (l&M) ? v[l^M] : v[l]   (partner on hi lanes, self on lo)
//   B[l] = (l&M) ? v[l]   : v[l^M] (self on hi lanes, partner on lo)
// => exchange r = (l&M)?A:B ; butterfly sum = A+B ; m=(l&M)?B:A, p=(l&M)?A:B
template<int M>
__device__ __forceinline__ void plswap1(float v, float &A, float &B){
    if constexpr (M == 16) {
        auto r = __builtin_amdgcn_permlane16_swap(__float_as_uint(v), __float_as_uint(v), false, false);
        A = __uint_as_float(r[0]); B = __uint_as_float(r[1]);
    } else {
        auto r = __builtin_amdgcn_permlane32_swap(__float_as_uint(v), __float_as_uint(v), false, false);
        A = __uint_as_float(r[0]); B = __uint_as_float(r[1]);
    }
}
// NOTE: cannot bind float& to ext_vector elements -> scalar temps + assign-back.
template<int M>
__device__ __forceinline__ void plswap2(f32x2 v, f32x2 &A, f32x2 &B){
    float ax, bx, ay, by;
    plswap1<M>(v.x, ax, bx);
    plswap1<M>(v.y, ay, by);
    A.x = ax; A.y = ay;
    B.x = bx; B.y = by;
}

// ===== cross-lane xor-exchange =====
// masks 1,2,8: single DPP (quad_perm 0xB1 / 0x4E, row_ror:8) — VALU pipe
// mask 4: 2x DPP (row_shl:4 / row_shr:4) + select — VALU pipe
// masks 16,32: permlane swap + select — VALU pipe (no DS ops anywhere)
template<int M>
__device__ __forceinline__ float lxf(float v){
    if constexpr (M == 1 || M == 2 || M == 8) {
        constexpr int ctrl = (M == 1) ? 0xB1 : (M == 2) ? 0x4E : 0x128;
        return __int_as_float(__builtin_amdgcn_update_dpp(
            0, __float_as_int(v), ctrl, 0xF, 0xF, true));
    } else if constexpr (M == 4) {
        float up = __int_as_float(__builtin_amdgcn_update_dpp(
            0, __float_as_int(v), 0x104, 0xF, 0xF, true));  // row_shl:4 -> v[l+4]
        float dn = __int_as_float(__builtin_amdgcn_update_dpp(
            0, __float_as_int(v), 0x114, 0xF, 0xF, true));  // row_shr:4 -> v[l-4]
        return (threadIdx.x & 4) ? dn : up;
    } else {
        float A, Bv; plswap1<M>(v, A, Bv);
        return (threadIdx.x & M) ? A : Bv;
    }
}
template<int M>
__device__ __forceinline__ f32x2 lx2(f32x2 v){
    f32x2 r; r.x = lxf<M>(v.x); r.y = lxf<M>(v.y); return r;
}
template<int M>
__device__ __forceinline__ cplx2 lxc(cplx2 a){
    cplx2 r; r.x = lx2<M>(a.x); r.y = lx2<M>(a.y); return r;
}

// ===== Rot gate, wire in reg bits: full pair update =====
template<int M, int R>
__device__ __forceinline__ void rot_reg(cplx2 (&a)[16],
        float u00x,float u00y,float u01x,float u01y,
        float u10x,float u10y,float u11x,float u11y){
    if constexpr (R < 16) {
        if constexpr ((R & M) == 0) {
            cplx2 a0 = a[R], a1 = a[R|M];
            a[R].x   = u00x*a0.x - u00y*a0.y + u01x*a1.x - u01y*a1.y;
            a[R].y   = u00x*a0.y + u00y*a0.x + u01x*a1.y + u01y*a1.x;
            a[R|M].x = u10x*a0.x - u10y*a0.y + u11x*a1.x - u11y*a1.y;
            a[R|M].y = u10x*a0.y + u10y*a0.x + u11x*a1.y + u11y*a1.x;
        }
        rot_reg<M,R+1>(a, u00x,u00y,u01x,u01y,u10x,u10y,u11x,u11y);
    }
}

// ===== Rot gate, wire in lane bits 0..3 (DPP exchange) =====
template<int LM, int R>
__device__ __forceinline__ void rot_lane(cplx2 (&a)[16],
        float uax,float uay,float ubx,float uby){
    if constexpr (R < 16) {
        cplx2 p = lxc<LM>(a[R]);
        cplx2 m = a[R];
        a[R].x = uax*m.x - uay*m.y + ubx*p.x - uby*p.y;
        a[R].y = uax*m.y + uay*m.x + ubx*p.y + uby*p.x;
        rot_lane<LM,R+1>(a, uax,uay,ubx,uby);
    }
}

// ===== Rot gate, wire in lane bits 4..5 (permlane A/B form) =====
// m=(l&M)?B:A, p=(l&M)?A:B folded into coefficients (hoisted per gate):
//   vax=(hi?ubx:uax) vay=(hi?uby:uay) vbx=(hi?uax:ubx) vby=(hi?uay:uby)
// a.x = vax*Ax - vay*Ay + vbx*Bx - vby*By
// a.y = vax*Ay + vay*Ax + vbx*By + vby*Bx
template<int M, int R>
__device__ __forceinline__ void rot_lane_pl(cplx2 (&a)[16],
        float vax,float vay,float vbx,float vby){
    if constexpr (R < 16) {
        f32x2 Ax,Bx,Ay,By;
        plswap2<M>(a[R].x, Ax, Bx);
        plswap2<M>(a[R].y, Ay, By);
        a[R].x = vax*Ax - vay*Ay + vbx*Bx - vby*By;
        a[R].y = vax*Ay + vay*Ax + vbx*By + vby*Bx;
        rot_lane_pl<M,R+1>(a, vax,vay,vbx,vby);
    }
}

// ===== CRX(pi/3): symmetric pair op  n = al*mine - i*be*partner =====

template<int MC, int MT, int R>
__device__ __forceinline__ void crx_rr(cplx2 (&a)[16], float cc, float ss){
    if constexpr (R < 16) {
        if constexpr ((R & MC) != 0 && (R & MT) == 0) {
            cplx2 a0 = a[R], a1 = a[R|MT];
            a[R].x    = cc*a0.x + ss*a1.y;  a[R].y    = cc*a0.y - ss*a1.x;
            a[R|MT].x = cc*a1.x + ss*a0.y;  a[R|MT].y = cc*a1.y - ss*a0.x;
        }
        crx_rr<MC,MT,R+1>(a, cc, ss);
    }
}

template<int MC, int LM, int R>
__device__ __forceinline__ void crx_rl(cplx2 (&a)[16], float cc, float ss){
    if constexpr (R < 16) {
        if constexpr ((R & MC) != 0) {
            cplx2 p = lxc<LM>(a[R]);
            cplx2 m = a[R];
            a[R].x = cc*m.x + ss*p.y;
            a[R].y = cc*m.y - ss*p.x;
        }
        crx_rl<MC,LM,R+1>(a, cc, ss);
    }
}

template<int MT, int R>
__device__ __forceinline__ void crx_lr(cplx2 (&a)[16], float al, float be){
    if constexpr (R < 16) {
        if constexpr ((R & MT) == 0) {
            cplx2 a0 = a[R], a1 = a[R|MT];
            a[R].x    = al*a0.x + be*a1.y;  a[R].y    = al*a0.y - be*a1.x;
            a[R|MT].x = al*a1.x + be*a0.y;  a[R|MT].y = al*a1.y - be*a0.x;
        }
        crx_lr<MT,R+1>(a, al, be);
    }
}

template<int TLM, int R>
__device__ __forceinline__ void crx_ll(cplx2 (&a)[16], float al, float be){
    if constexpr (R < 16) {
        cplx2 p = lxc<TLM>(a[R]);
        cplx2 m = a[R];
        a[R].x = al*m.x + be*p.y;
        a[R].y = al*m.y - be*p.x;
        crx_ll<TLM,R+1>(a, al, be);
    }
}

// CRX with target in lane bits 4..5 (permlane A/B form):
// a.x = al*m.x + be*p.y = kmA*Ax + kmB*Bx + kpA*Ay + kpB*By
// a.y = al*m.y - be*p.x = kmA*Ay + kmB*By - kpA*Ax - kpB*Bx
// kmA=(bt?0:al) kmB=(bt?al:0) kpA=(bt?be:0) kpB=(bt?0:be), bt = target lane bit
template<int M, int R>
__device__ __forceinline__ void crx_ll_pl(cplx2 (&a)[16],
        float kmA,float kmB,float kpA,float kpB){
    if constexpr (R < 16) {
        f32x2 Ax,Bx,Ay,By;
        plswap2<M>(a[R].x, Ax, Bx);
        plswap2<M>(a[R].y, Ay, By);
        a[R].x = kmA*Ax + kmB*Bx + kpA*Ay + kpB*By;
        a[R].y = kmA*Ay + kmB*By - kpA*Ax - kpB*Bx;
        crx_ll_pl<M,R+1>(a, kmA,kmB,kpA,kpB);
    }
}

// ===== JIT Rot gate (RZ(omega) elided: commutes to the CNOT cascade = basis
// permutation, vanishes under |.|^2.  Rot -> RY(th)RZ(phi)) =====
template<int I>
__device__ __forceinline__ void do_rot(cplx2 (&amp)[16], int lane, const float* __restrict__ w){
    float phi = w[I*3 + 0], th = w[I*3 + 1];
    float ct, st, cp, sp;
    __sincosf(0.5f * th,  &st, &ct);
    __sincosf(0.5f * phi, &sp, &cp);
    float A = ct*cp, Bv = ct*sp, C = st*cp, D = st*sp;
    // u00=(A,-B) u01=(-C,-D) u10=(C,-D) u11=(A,B)
    if constexpr (I < 4) {
        rot_reg<(1<<I),0>(amp, A,-Bv, -C,-D, C,-D, A,Bv);
    } else if constexpr (I < 8) {
        constexpr int LM = 1 << (I - 4);
        const bool hi = (lane & LM) != 0;
        float uax = A,            uay = hi ? Bv : -Bv;  // hi?u11:u00
        float ubx = hi ? C : -C,  uby = -D;             // hi?u10:u01
        rot_lane<LM,0>(amp, uax,uay,ubx,uby);
    } else {
        constexpr int LM = 1 << (I - 4);                // 16 or 32
        const bool hi = (lane & LM) != 0;
        // ua=hi?u11:u00, ub=hi?u10:u01 swapped into A/B-slot coeffs:
        float vax = hi ? C  : A;    // hi?ubx:uax
        float vay = hi ? -D : -Bv;  // hi?uby:uay
        float vbx = hi ? A  : -C;   // hi?uax:ubx
        float vby = hi ? Bv : -D;   // hi?uay:uby
        rot_lane_pl<LM,0>(amp, vax,vay,vbx,vby);
    }
}

// ===== measurement: 4 signed sums, CNOT cascade folded into parity masks =====
template<int R>
__device__ __forceinline__ void accum4(const cplx2 (&a)[16], f32x2 &SA, f32x2 &SB, f32x2 &SC, f32x2 &SD){
    if constexpr (R < 16) {
        f32x2 p = a[R].x*a[R].x + a[R].y*a[R].y;
        SA += ((R>>2) & 1)            ? -p : p;
        SB += ((R>>3) & 1)            ? -p : p;
        SC += ((R ^ (R>>2)) & 1)      ? -p : p;
        SD += (((R>>1) ^ (R>>3)) & 1) ? -p : p;
        accum4<R+1>(a, SA, SB, SC, SD);
    }
}

__device__ __forceinline__ f32x2 wave_sum2(f32x2 v){
    v += lx2< 1>(v);
    v += lx2< 2>(v);
    v += lx2< 4>(v);
    v += lx2< 8>(v);
    f32x2 A, B;
    plswap2<16>(v, A, B); v = A + B;   // butterfly sum, no select needed
    plswap2<32>(v, A, B); v = A + B;
    return v;
}

// 64-point Walsh-Hadamard over lanes: output lane l = sum_j (-1)^{popcount(j&l)} x_j
__device__ __forceinline__ f32x2 wht2(f32x2 v, int lane){
    f32x2 p;
    p = lx2< 1>(v); v = (lane &  1) ? p - v : v + p;
    p = lx2< 2>(v); v = (lane &  2) ? p - v : v + p;
    p = lx2< 4>(v); v = (lane &  4) ? p - v : v + p;
    p = lx2< 8>(v); v = (lane &  8) ? p - v : v + p;
    f32x2 A, B;
    plswap2<16>(v, A, B); v = (lane & 16) ? A - B : A + B;  // p-v : v+p
    plswap2<32>(v, A, B); v = (lane & 32) ? A - B : A + B;
    return v;
}

__device__ __forceinline__ f32x2 fsgn2(f32x2 v, unsigned s){
    f32x2 r;
    r.x = __uint_as_float(__float_as_uint(v.x) ^ s);
    r.y = __uint_as_float(__float_as_uint(v.y) ^ s);
    return r;
}
__device__ __forceinline__ unsigned parsgn(int lane, int m){
    return (unsigned)((__builtin_popcount(lane & m) & 1)) << 31;
}

// (256,4): VGPR cap 128 — cplx2 working set ~90-110, proven no-spill regime (R5/R6).
__global__ __launch_bounds__(256, 4) void qsim_kernel(const float* __restrict__ inputs,
                                                      const float* __restrict__ weights,
                                                      float* __restrict__ out, int B, int nPairs){
    const int lane = threadIdx.x & 63;
    const int pair = __builtin_amdgcn_readfirstlane((int)((blockIdx.x * blockDim.x + threadIdx.x) >> 6));
    if (pair >= nPairs) return;

    const int s0 = 2 * pair;
    const int s1 = (s0 + 1 < B) ? s0 + 1 : s0;   // tail-safe load index
    const float* ang0 = inputs + (size_t)s0 * NQ;
    const float* ang1 = inputs + (size_t)s1 * NQ;

    // ---- lane-qubit factor F (per sample), one sincos live at a time ----
    f32x2 F = 1.f;
    #pragma unroll
    for (int w = 4; w < NQ; ++w) {
        float sA, cA, sB, cB;
        __sincosf(0.5f * ang0[w], &sA, &cA);
        __sincosf(0.5f * ang1[w], &sB, &cB);
        bool hi = (lane & (1 << (w - 4))) != 0;
        f32x2 f; f.x = hi ? sA : cA; f.y = hi ? sB : cB;
        F *= f;
    }

    // ---- reg-qubit product state ----
    f32x2 c[4], s[4];
    #pragma unroll
    for (int w = 0; w < 4; ++w) {
        float sA, cA, sB, cB;
        __sincosf(0.5f * ang0[w], &sA, &cA);
        __sincosf(0.5f * ang1[w], &sB, &cB);
        c[w].x = cA; c[w].y = cB; s[w].x = sA; s[w].y = sB;
    }

    f32x2 v2a = F * c[0], v2b = F * s[0];
    f32x2 v4[4] = { v2a*c[1], v2b*c[1], v2a*s[1], v2b*s[1] };
    f32x2 v8[8] = { v4[0]*c[2], v4[1]*c[2], v4[2]*c[2], v4[3]*c[2],
                    v4[0]*s[2], v4[1]*s[2], v4[2]*s[2], v4[3]*s[2] };

    cplx2 amp[16];
    #pragma unroll
    for (int r = 0; r < 8; ++r) {
        amp[r].x   = v8[r] * c[3]; amp[r].y   = 0.f;
        amp[r+8].x = v8[r] * s[3]; amp[r+8].y = 0.f;
    }

    // ---- CRX(pi/3) over chain edges (EDGES order) ----
    const float cc = 0.86602540378443864676f;  // cos(pi/6)
    const float ss = 0.5f;                     // sin(pi/6)
    crx_rr<1, 2, 0>(amp, cc, ss);                                    // (0,1)
    crx_rr<2, 4, 0>(amp, cc, ss);                                    // (1,2)
    crx_rr<4, 8, 0>(amp, cc, ss);                                    // (2,3)
    crx_rl<8, 1, 0>(amp, cc, ss);                                    // (3,4)  xor1 -> DPP
    { bool t = (lane &  1); crx_ll< 2,0>(amp, t?cc:1.f, t?ss:0.f); } // (4,5)  xor2 -> DPP
    { bool t = (lane &  2); crx_ll< 4,0>(amp, t?cc:1.f, t?ss:0.f); } // (5,6)  xor4 -> 2xDPP
    { bool t = (lane &  4); crx_ll< 8,0>(amp, t?cc:1.f, t?ss:0.f); } // (6,7)  xor8 -> DPP
    { bool t = (lane &  8); bool bt = (lane & 16);                   // (7,8)  xor16 -> permlane
      float al = t?cc:1.f, be = t?ss:0.f;
      crx_ll_pl<16,0>(amp, bt?0.f:al, bt?al:0.f, bt?be:0.f, bt?0.f:be); }
    { bool t = (lane & 16); bool bt = (lane & 32);                   // (8,9)  xor32 -> permlane
      float al = t?cc:1.f, be = t?ss:0.f;
      crx_ll_pl<32,0>(amp, bt?0.f:al, bt?al:0.f, bt?be:0.f, bt?0.f:be); }
    { bool t = (lane & 32); crx_lr< 1,0>(amp, t?cc:1.f, t?ss:0.f); } // (9,0)  no shuffle

    // ---- StronglyEntanglingLayers Rot gates (RZ(omega) elided) ----
    do_rot<0>(amp, lane, weights);
    do_rot<1>(amp, lane, weights);
    do_rot<2>(amp, lane, weights);
    do_rot<3>(amp, lane, weights);
    do_rot<4>(amp, lane, weights);
    do_rot<5>(amp, lane, weights);
    do_rot<6>(amp, lane, weights);
    do_rot<7>(amp, lane, weights);
    do_rot<8>(amp, lane, weights);
    do_rot<9>(amp, lane, weights);

    // ---- measurement: CNOT cascade folded into parity masks ----
    // Outputs: o0:(SA,21) o1:(SB,42); SC family masks {0,1,5,21} -> o{2,4,6,8};
    // SD family masks {0,2,10,42} -> o{3,5,7,9}.  WHT lane l = mask-l signed sum.
    f32x2 SA = 0.f, SB = 0.f, SC = 0.f, SD = 0.f;
    accum4<0>(amp, SA, SB, SC, SD);

    f32x2 r0  = wave_sum2(fsgn2(SA, parsgn(lane, 21)));
    f32x2 r1  = wave_sum2(fsgn2(SB, parsgn(lane, 42)));
    f32x2 wsc = wht2(SC, lane);
    f32x2 wsd = wht2(SD, lane);

    float* o0 = out + (size_t)s0 * NQ;
    const bool has1 = (s0 + 1 < B);
    float* o1 = out + (size_t)(s0 + 1) * NQ;

    if (lane == 0) {
        o0[0] = r0.x; o0[1] = r1.x; o0[2] = wsc.x; o0[3] = wsd.x;
        if (has1) { o1[0] = r0.y; o1[1] = r1.y; o1[2] = wsc.y; o1[3] = wsd.y; }
    } else if (lane == 1) {
        o0[4] = wsc.x; if (has1) o1[4] = wsc.y;
    } else if (lane == 5) {
        o0[6] = wsc.x; if (has1) o1[6] = wsc.y;
    } else if (lane == 21) {
        o0[8] = wsc.x; if (has1) o1[8] = wsc.y;
    } else if (lane == 2) {
        o0[5] = wsd.x; if (has1) o1[5] = wsd.y;
    } else if (lane == 10) {
        o0[7] = wsd.x; if (has1) o1[7] = wsd.y;
    } else if (lane == 42) {
        o0[9] = wsd.x; if (has1) o1[9] = wsd.y;
    }
}

extern "C" void kernel_launch(void* const* d_in, const int* in_sizes, int n_in,
                              void* d_out, int out_size, void* d_ws, size_t ws_size,
                              hipStream_t stream) {
    const float* inputs  = (const float*)d_in[0];   // (B, 10) float32
    const float* weights = (const float*)d_in[1];   // (1, 10, 3) float32
    float* out = (float*)d_out;                     // (B, 10) float32
    const int B = in_sizes[0] / NQ;
    const int nPairs = (B + 1) / 2;                 // one wave per 2 samples
    const int wavesPerBlock = 256 / 64;
    const int blocks = (nPairs + wavesPerBlock - 1) / wavesPerBlock;
    qsim_kernel<<<blocks, 256, 0, stream>>>(inputs, weights, out, B, nPairs);
}

// Round 8
// 80.008 us; speedup vs baseline: 1.0518x; 1.0518x over previous
//
#include <hip/hip_runtime.h>

#define NQ 10

typedef float f32x2 __attribute__((ext_vector_type(2)));
struct cplx2 { f32x2 x, y; };  // .x/.y = real/imag; each f32x2 = (sample0, sample1)

// ===== permlane swap (VALU pipe; A/B semantics verified correct in R7) =====
// {A,B} = permlaneN_swap(v,v):
//   A[l] = (l&M) ? v[l^M] : v[l]   (partner on hi lanes, self on lo)
//   B[l] = (l&M) ? v[l]   : v[l^M] (self on hi lanes, partner on lo)
// => exchange r = (l&M)?A:B ; butterfly sum = A+B ; m=(l&M)?B:A, p=(l&M)?A:B
template<int M>
__device__ __forceinline__ void plswap1(float v, float &A, float &B){
    if constexpr (M == 16) {
        auto r = __builtin_amdgcn_permlane16_swap(__float_as_uint(v), __float_as_uint(v), false, false);
        A = __uint_as_float(r[0]); B = __uint_as_float(r[1]);
    } else {
        auto r = __builtin_amdgcn_permlane32_swap(__float_as_uint(v), __float_as_uint(v), false, false);
        A = __uint_as_float(r[0]); B = __uint_as_float(r[1]);
    }
}
// NOTE: cannot bind float& to ext_vector elements -> scalar temps + assign-back.
template<int M>
__device__ __forceinline__ void plswap2(f32x2 v, f32x2 &A, f32x2 &B){
    float ax, bx, ay, by;
    plswap1<M>(v.x, ax, bx);
    plswap1<M>(v.y, ay, by);
    A.x = ax; A.y = ay;
    B.x = bx; B.y = by;
}

// ===== cross-lane xor-exchange =====
// masks 1,2,8: single DPP (quad_perm 0xB1 / 0x4E, row_ror:8) — VALU pipe
// mask 4: 2x DPP (row_shl:4 / row_shr:4) + select — VALU pipe
// masks 16,32: permlane swap + select — VALU pipe (no DS ops anywhere)
template<int M>
__device__ __forceinline__ float lxf(float v){
    if constexpr (M == 1 || M == 2 || M == 8) {
        constexpr int ctrl = (M == 1) ? 0xB1 : (M == 2) ? 0x4E : 0x128;
        return __int_as_float(__builtin_amdgcn_update_dpp(
            0, __float_as_int(v), ctrl, 0xF, 0xF, true));
    } else if constexpr (M == 4) {
        float up = __int_as_float(__builtin_amdgcn_update_dpp(
            0, __float_as_int(v), 0x104, 0xF, 0xF, true));  // row_shl:4 -> v[l+4]
        float dn = __int_as_float(__builtin_amdgcn_update_dpp(
            0, __float_as_int(v), 0x114, 0xF, 0xF, true));  // row_shr:4 -> v[l-4]
        return (threadIdx.x & 4) ? dn : up;
    } else {
        float A, Bv; plswap1<M>(v, A, Bv);
        return (threadIdx.x & M) ? A : Bv;
    }
}
template<int M>
__device__ __forceinline__ f32x2 lx2(f32x2 v){
    f32x2 r; r.x = lxf<M>(v.x); r.y = lxf<M>(v.y); return r;
}
template<int M>
__device__ __forceinline__ cplx2 lxc(cplx2 a){
    cplx2 r; r.x = lx2<M>(a.x); r.y = lx2<M>(a.y); return r;
}

// ===== RY gate (real 2x2), wire in reg bits =====
template<int M, int R>
__device__ __forceinline__ void ry_reg(cplx2 (&a)[16], float c, float s){
    if constexpr (R < 16) {
        if constexpr ((R & M) == 0) {
            cplx2 a0 = a[R], a1 = a[R|M];
            a[R].x   = c*a0.x - s*a1.x;  a[R].y   = c*a0.y - s*a1.y;
            a[R|M].x = s*a0.x + c*a1.x;  a[R|M].y = s*a0.y + c*a1.y;
        }
        ry_reg<M,R+1>(a, c, s);
    }
}

// ===== RY gate, wire in lane bits 0..3 (DPP): m' = c*m + se*p, se=hi?+s:-s =====
template<int LM, int R>
__device__ __forceinline__ void ry_lane(cplx2 (&a)[16], float c, float se){
    if constexpr (R < 16) {
        cplx2 p = lxc<LM>(a[R]);
        cplx2 m = a[R];
        a[R].x = c*m.x + se*p.x;
        a[R].y = c*m.y + se*p.y;
        ry_lane<LM,R+1>(a, c, se);
    }
}

// ===== RY gate, wire in lane bits 4..5 (permlane A/B form) =====
// m=(l&M)?B:A, p=(l&M)?A:B; m' = c*m + se*p = kA*A + kB*B
// hi: kA=s, kB=c ;  lo: kA=c, kB=-s   (hoisted per gate)
template<int M, int R>
__device__ __forceinline__ void ry_lane_pl(cplx2 (&a)[16], float kA, float kB){
    if constexpr (R < 16) {
        f32x2 Ax,Bx,Ay,By;
        plswap2<M>(a[R].x, Ax, Bx);
        plswap2<M>(a[R].y, Ay, By);
        a[R].x = kA*Ax + kB*Bx;
        a[R].y = kA*Ay + kB*By;
        ry_lane_pl<M,R+1>(a, kA, kB);
    }
}

// ===== CRX(pi/3): symmetric pair op  n = al*mine - i*be*partner =====

template<int MC, int MT, int R>
__device__ __forceinline__ void crx_rr(cplx2 (&a)[16], float cc, float ss){
    if constexpr (R < 16) {
        if constexpr ((R & MC) != 0 && (R & MT) == 0) {
            cplx2 a0 = a[R], a1 = a[R|MT];
            a[R].x    = cc*a0.x + ss*a1.y;  a[R].y    = cc*a0.y - ss*a1.x;
            a[R|MT].x = cc*a1.x + ss*a0.y;  a[R|MT].y = cc*a1.y - ss*a0.x;
        }
        crx_rr<MC,MT,R+1>(a, cc, ss);
    }
}

template<int MC, int LM, int R>
__device__ __forceinline__ void crx_rl(cplx2 (&a)[16], float cc, float ss){
    if constexpr (R < 16) {
        if constexpr ((R & MC) != 0) {
            cplx2 p = lxc<LM>(a[R]);
            cplx2 m = a[R];
            a[R].x = cc*m.x + ss*p.y;
            a[R].y = cc*m.y - ss*p.x;
        }
        crx_rl<MC,LM,R+1>(a, cc, ss);
    }
}

template<int MT, int R>
__device__ __forceinline__ void crx_lr(cplx2 (&a)[16], float al, float be){
    if constexpr (R < 16) {
        if constexpr ((R & MT) == 0) {
            cplx2 a0 = a[R], a1 = a[R|MT];
            a[R].x    = al*a0.x + be*a1.y;  a[R].y    = al*a0.y - be*a1.x;
            a[R|MT].x = al*a1.x + be*a0.y;  a[R|MT].y = al*a1.y - be*a0.x;
        }
        crx_lr<MT,R+1>(a, al, be);
    }
}

template<int TLM, int R>
__device__ __forceinline__ void crx_ll(cplx2 (&a)[16], float al, float be){
    if constexpr (R < 16) {
        cplx2 p = lxc<TLM>(a[R]);
        cplx2 m = a[R];
        a[R].x = al*m.x + be*p.y;
        a[R].y = al*m.y - be*p.x;
        crx_ll<TLM,R+1>(a, al, be);
    }
}

// CRX with target in lane bits 4..5 (permlane A/B form):
// kmA=(bt?0:al) kmB=(bt?al:0) kpA=(bt?be:0) kpB=(bt?0:be), bt = target lane bit
template<int M, int R>
__device__ __forceinline__ void crx_ll_pl(cplx2 (&a)[16],
        float kmA,float kmB,float kpA,float kpB){
    if constexpr (R < 16) {
        f32x2 Ax,Bx,Ay,By;
        plswap2<M>(a[R].x, Ax, Bx);
        plswap2<M>(a[R].y, Ay, By);
        a[R].x = kmA*Ax + kmB*Bx + kpA*Ay + kpB*By;
        a[R].y = kmA*Ay + kmB*By - kpA*Ax - kpB*Bx;
        crx_ll_pl<M,R+1>(a, kmA,kmB,kpA,kpB);
    }
}

// ===== RY dispatcher (Rot = RY(th)*RZ(phi); RZ(phi) hoisted to the fused
// phase pass below; RZ(omega) elided: commutes to CNOT cascade, dies in |.|^2) =====
template<int I>
__device__ __forceinline__ void do_ry(cplx2 (&amp)[16], int lane, const float* __restrict__ w){
    float c, s;
    __sincosf(0.5f * w[I*3 + 1], &s, &c);
    if constexpr (I < 4) {
        ry_reg<(1<<I),0>(amp, c, s);
    } else if constexpr (I < 8) {
        constexpr int LM = 1 << (I - 4);
        const bool hi = (lane & LM) != 0;
        ry_lane<LM,0>(amp, c, hi ? s : -s);
    } else {
        constexpr int LM = 1 << (I - 4);                // 16 or 32
        const bool hi = (lane & LM) != 0;
        ry_lane_pl<LM,0>(amp, hi ? s : c, hi ? c : -s);
    }
}

// ===== measurement: 4 signed sums, CNOT cascade folded into parity masks =====
template<int R>
__device__ __forceinline__ void accum4(const cplx2 (&a)[16], f32x2 &SA, f32x2 &SB, f32x2 &SC, f32x2 &SD){
    if constexpr (R < 16) {
        f32x2 p = a[R].x*a[R].x + a[R].y*a[R].y;
        SA += ((R>>2) & 1)            ? -p : p;
        SB += ((R>>3) & 1)            ? -p : p;
        SC += ((R ^ (R>>2)) & 1)      ? -p : p;
        SD += (((R>>1) ^ (R>>3)) & 1) ? -p : p;
        accum4<R+1>(a, SA, SB, SC, SD);
    }
}

__device__ __forceinline__ f32x2 wave_sum2(f32x2 v){
    v += lx2< 1>(v);
    v += lx2< 2>(v);
    v += lx2< 4>(v);
    v += lx2< 8>(v);
    f32x2 A, B;
    plswap2<16>(v, A, B); v = A + B;   // butterfly sum, no select needed
    plswap2<32>(v, A, B); v = A + B;
    return v;
}

// 64-point Walsh-Hadamard over lanes: output lane l = sum_j (-1)^{popcount(j&l)} x_j
__device__ __forceinline__ f32x2 wht2(f32x2 v, int lane){
    f32x2 p;
    p = lx2< 1>(v); v = (lane &  1) ? p - v : v + p;
    p = lx2< 2>(v); v = (lane &  2) ? p - v : v + p;
    p = lx2< 4>(v); v = (lane &  4) ? p - v : v + p;
    p = lx2< 8>(v); v = (lane &  8) ? p - v : v + p;
    f32x2 A, B;
    plswap2<16>(v, A, B); v = (lane & 16) ? A - B : A + B;  // p-v : v+p
    plswap2<32>(v, A, B); v = (lane & 32) ? A - B : A + B;
    return v;
}

__device__ __forceinline__ f32x2 fsgn2(f32x2 v, unsigned s){
    f32x2 r;
    r.x = __uint_as_float(__float_as_uint(v.x) ^ s);
    r.y = __uint_as_float(__float_as_uint(v.y) ^ s);
    return r;
}
__device__ __forceinline__ unsigned parsgn(int lane, int m){
    return (unsigned)((__builtin_popcount(lane & m) & 1)) << 31;
}

// (256,4): VGPR cap 128 — cplx2 working set ~90-110, proven no-spill regime (R5/R6).
__global__ __launch_bounds__(256, 4) void qsim_kernel(const float* __restrict__ inputs,
                                                      const float* __restrict__ weights,
                                                      float* __restrict__ out, int B, int nPairs){
    const int lane = threadIdx.x & 63;
    const int pair = __builtin_amdgcn_readfirstlane((int)((blockIdx.x * blockDim.x + threadIdx.x) >> 6));
    if (pair >= nPairs) return;

    const int s0 = 2 * pair;
    const int s1 = (s0 + 1 < B) ? s0 + 1 : s0;   // tail-safe load index
    const float* ang0 = inputs + (size_t)s0 * NQ;
    const float* ang1 = inputs + (size_t)s1 * NQ;

    // ---- lane-qubit factor F (per sample), one sincos live at a time ----
    f32x2 F = 1.f;
    #pragma unroll
    for (int w = 4; w < NQ; ++w) {
        float sA, cA, sB, cB;
        __sincosf(0.5f * ang0[w], &sA, &cA);
        __sincosf(0.5f * ang1[w], &sB, &cB);
        bool hi = (lane & (1 << (w - 4))) != 0;
        f32x2 f; f.x = hi ? sA : cA; f.y = hi ? sB : cB;
        F *= f;
    }

    // ---- reg-qubit product state ----
    f32x2 c[4], s[4];
    #pragma unroll
    for (int w = 0; w < 4; ++w) {
        float sA, cA, sB, cB;
        __sincosf(0.5f * ang0[w], &sA, &cA);
        __sincosf(0.5f * ang1[w], &sB, &cB);
        c[w].x = cA; c[w].y = cB; s[w].x = sA; s[w].y = sB;
    }

    f32x2 v2a = F * c[0], v2b = F * s[0];
    f32x2 v4[4] = { v2a*c[1], v2b*c[1], v2a*s[1], v2b*s[1] };
    f32x2 v8[8] = { v4[0]*c[2], v4[1]*c[2], v4[2]*c[2], v4[3]*c[2],
                    v4[0]*s[2], v4[1]*s[2], v4[2]*s[2], v4[3]*s[2] };

    cplx2 amp[16];
    #pragma unroll
    for (int r = 0; r < 8; ++r) {
        amp[r].x   = v8[r] * c[3]; amp[r].y   = 0.f;
        amp[r+8].x = v8[r] * s[3]; amp[r+8].y = 0.f;
    }

    // ---- CRX(pi/3) over chain edges (EDGES order) ----
    const float cc = 0.86602540378443864676f;  // cos(pi/6)
    const float ss = 0.5f;                     // sin(pi/6)
    crx_rr<1, 2, 0>(amp, cc, ss);                                    // (0,1)
    crx_rr<2, 4, 0>(amp, cc, ss);                                    // (1,2)
    crx_rr<4, 8, 0>(amp, cc, ss);                                    // (2,3)
    crx_rl<8, 1, 0>(amp, cc, ss);                                    // (3,4)  xor1 -> DPP
    { bool t = (lane &  1); crx_ll< 2,0>(amp, t?cc:1.f, t?ss:0.f); } // (4,5)  xor2 -> DPP
    { bool t = (lane &  2); crx_ll< 4,0>(amp, t?cc:1.f, t?ss:0.f); } // (5,6)  xor4 -> 2xDPP
    { bool t = (lane &  4); crx_ll< 8,0>(amp, t?cc:1.f, t?ss:0.f); } // (6,7)  xor8 -> DPP
    { bool t = (lane &  8); bool bt = (lane & 16);                   // (7,8)  xor16 -> permlane
      float al = t?cc:1.f, be = t?ss:0.f;
      crx_ll_pl<16,0>(amp, bt?0.f:al, bt?al:0.f, bt?be:0.f, bt?0.f:be); }
    { bool t = (lane & 16); bool bt = (lane & 32);                   // (8,9)  xor32 -> permlane
      float al = t?cc:1.f, be = t?ss:0.f;
      crx_ll_pl<32,0>(amp, bt?0.f:al, bt?al:0.f, bt?be:0.f, bt?0.f:be); }
    { bool t = (lane & 32); crx_lr< 1,0>(amp, t?cc:1.f, t?ss:0.f); } // (9,0)  no shuffle

    // ---- fused RZ(phi) phase pass: all ten RZ(phi_i) commute across wires,
    // merged into ONE diagonal e^{i*sigma}, sigma = sum_w (bit_w? +phi_w/2 : -phi_w/2).
    // RZ(phi_w) = diag(e^{-i phi/2}, e^{+i phi/2}); weights are sample-independent.
    {
        float cp[NQ], sp[NQ];
        #pragma unroll
        for (int i = 0; i < NQ; ++i)
            __sincosf(0.5f * weights[i*3 + 0], &sp[i], &cp[i]);

        // lane part (wires 4..9): per-thread scalar complex product
        float Lr = 1.f, Li = 0.f;
        #pragma unroll
        for (int wq = 4; wq < NQ; ++wq) {
            float sg = (lane & (1 << (wq - 4))) ? sp[wq] : -sp[wq];
            float nr = Lr*cp[wq] - Li*sg;
            float ni = Li*cp[wq] + Lr*sg;
            Lr = nr; Li = ni;
        }

        // reg-part product tree over wires 0..2 (seeded with lane phase)
        float er[8], ei[8];
        er[0] = Lr; ei[0] = Li;
        #pragma unroll
        for (int q = 0; q < 3; ++q) {
            const int n = 1 << q;
            #pragma unroll
            for (int r = n - 1; r >= 0; --r) {
                float ar = er[r], ai = ei[r];
                er[r+n] = ar*cp[q] - ai*sp[q];   // bit=1: *(c + i s)
                ei[r+n] = ai*cp[q] + ar*sp[q];
                er[r]   = ar*cp[q] + ai*sp[q];   // bit=0: *(c - i s)
                ei[r]   = ai*cp[q] - ar*sp[q];
            }
        }
        // wire 3 fused with apply (amp[r] ~ bit3=0, amp[r+8] ~ bit3=1)
        #pragma unroll
        for (int r = 0; r < 8; ++r) {
            float g0r = er[r]*cp[3] + ei[r]*sp[3], g0i = ei[r]*cp[3] - er[r]*sp[3];
            float g1r = er[r]*cp[3] - ei[r]*sp[3], g1i = ei[r]*cp[3] + er[r]*sp[3];
            f32x2 x, y;
            x = amp[r].x;   y = amp[r].y;
            amp[r].x   = x*g0r - y*g0i;  amp[r].y   = y*g0r + x*g0i;
            x = amp[r+8].x; y = amp[r+8].y;
            amp[r+8].x = x*g1r - y*g1i;  amp[r+8].y = y*g1r + x*g1i;
        }
    }

    // ---- StronglyEntanglingLayers: now pure-real RY gates ----
    do_ry<0>(amp, lane, weights);
    do_ry<1>(amp, lane, weights);
    do_ry<2>(amp, lane, weights);
    do_ry<3>(amp, lane, weights);
    do_ry<4>(amp, lane, weights);
    do_ry<5>(amp, lane, weights);
    do_ry<6>(amp, lane, weights);
    do_ry<7>(amp, lane, weights);
    do_ry<8>(amp, lane, weights);
    do_ry<9>(amp, lane, weights);

    // ---- measurement: CNOT cascade folded into parity masks ----
    // Outputs: o0:(SA,21) o1:(SB,42); SC family masks {0,1,5,21} -> o{2,4,6,8};
    // SD family masks {0,2,10,42} -> o{3,5,7,9}.  WHT lane l = mask-l signed sum.
    f32x2 SA = 0.f, SB = 0.f, SC = 0.f, SD = 0.f;
    accum4<0>(amp, SA, SB, SC, SD);

    f32x2 r0  = wave_sum2(fsgn2(SA, parsgn(lane, 21)));
    f32x2 r1  = wave_sum2(fsgn2(SB, parsgn(lane, 42)));
    f32x2 wsc = wht2(SC, lane);
    f32x2 wsd = wht2(SD, lane);

    float* o0 = out + (size_t)s0 * NQ;
    const bool has1 = (s0 + 1 < B);
    float* o1 = out + (size_t)(s0 + 1) * NQ;

    if (lane == 0) {
        o0[0] = r0.x; o0[1] = r1.x; o0[2] = wsc.x; o0[3] = wsd.x;
        if (has1) { o1[0] = r0.y; o1[1] = r1.y; o1[2] = wsc.y; o1[3] = wsd.y; }
    } else if (lane == 1) {
        o0[4] = wsc.x; if (has1) o1[4] = wsc.y;
    } else if (lane == 5) {
        o0[6] = wsc.x; if (has1) o1[6] = wsc.y;
    } else if (lane == 21) {
        o0[8] = wsc.x; if (has1) o1[8] = wsc.y;
    } else if (lane == 2) {
        o0[5] = wsd.x; if (has1) o1[5] = wsd.y;
    } else if (lane == 10) {
        o0[7] = wsd.x; if (has1) o1[7] = wsd.y;
    } else if (lane == 42) {
        o0[9] = wsd.x; if (has1) o1[9] = wsd.y;
    }
}

extern "C" void kernel_launch(void* const* d_in, const int* in_sizes, int n_in,
                              void* d_out, int out_size, void* d_ws, size_t ws_size,
                              hipStream_t stream) {
    const float* inputs  = (const float*)d_in[0];   // (B, 10) float32
    const float* weights = (const float*)d_in[1];   // (1, 10, 3) float32
    float* out = (float*)d_out;                     // (B, 10) float32
    const int B = in_sizes[0] / NQ;
    const int nPairs = (B + 1) / 2;                 // one wave per 2 samples
    const int wavesPerBlock = 256 / 64;
    const int blocks = (nPairs + wavesPerBlock - 1) / wavesPerBlock;
    qsim_kernel<<<blocks, 256, 0, stream>>>(inputs, weights, out, B, nPairs);
}